// Round 3
// baseline (158.326 us; speedup 1.0000x reference)
//
#include <hip/hip_runtime.h>
#include <hip/hip_bf16.h>

#define N_ATOMS   200000
#define D_IN      256
#define D_OUT     256
#define N_SPECIES 4
#define N_STRUCT  2000
#define M_PAD     2048      // padded struct rows (zero-filled tail)
#define KFLAT     1024      // N_SPECIES * D_IN

typedef __attribute__((ext_vector_type(8))) short bf16x8;
typedef __attribute__((ext_vector_type(4))) float f32x4;

__device__ inline unsigned short f2bf(float f) {
    unsigned int u = __float_as_uint(f);
    unsigned int r = (u + 0x7fffu + ((u >> 16) & 1u)) >> 16;   // RNE
    return (unsigned short)r;
}

// ---- ws layout (bytes) ----
// 0        : Wt bf16 [16][256][64]          = 524288   (K-block-major, kbg = s*4+kb)
// 524288   : S  f32 [2048][1024]            = 8388608  (row g, col s*256+k)
// 8912896  : cnt f32 [2048][4]              = 32768
// total 8945664

// K1: convert + transpose W -> Wt[kbg][n][kp], kbg = s*4 + (k>>6)
__global__ void k_wt(const float* __restrict__ W, unsigned short* __restrict__ Wt) {
    int k = blockIdx.x;        // 0..255
    int n = threadIdx.x;       // 0..255
    for (int s = 0; s < N_SPECIES; ++s) {
        float v = W[((size_t)s * 256 + k) * 256 + n];
        Wt[(((size_t)(s * 4 + (k >> 6)) * 256 + n) * 64) + (k & 63)] = f2bf(v);
    }
}

// K2: segment-sum x into S[(g)][s*256+k] + counts cnt[g*4+s].
// Block = 4 waves x 32 contiguous atoms; lane owns 4 columns (float4).
__global__ __launch_bounds__(256) void k_seg(
        const float* __restrict__ x, const int* __restrict__ spec,
        const int* __restrict__ sidx, float* __restrict__ S,
        float* __restrict__ cnt) {

    __shared__ int lkeys[128];
    int t = threadIdx.x;
    int a0blk = blockIdx.x * 128;
    if (t < 128) {
        int a = a0blk + t;
        lkeys[t] = (a < N_ATOMS) ? (sidx[a] * 4 + spec[a]) : ((M_PAD - 1) * 4);
    }
    __syncthreads();

    int wave = t >> 6, lane = t & 63;
    int a0 = a0blk + wave * 32;
    if (a0 >= N_ATOMS) return;          // fully-invalid waves only (200000 % 32 == 0)
    int koff = wave * 32;

    const float4* xp4 = (const float4*)(x + (size_t)a0 * 256 + lane * 4);
    // per-row stride in float4 units = 64

    float acc[4][4];
    float cs[4];
#pragma unroll
    for (int s = 0; s < 4; ++s) {
        cs[s] = 0.f;
#pragma unroll
        for (int c = 0; c < 4; ++c) acc[s][c] = 0.f;
    }
    int cur = lkeys[koff] >> 2;

#define FLUSH_RUN()                                                          \
    do {                                                                     \
        _Pragma("unroll")                                                    \
        for (int s = 0; s < 4; ++s) {                                        \
            if (cs[s] != 0.f) {                                              \
                float* p = S + ((size_t)cur << 10) + (s << 8) + (lane << 2); \
                atomicAdd(p + 0, acc[s][0]);                                 \
                atomicAdd(p + 1, acc[s][1]);                                 \
                atomicAdd(p + 2, acc[s][2]);                                 \
                atomicAdd(p + 3, acc[s][3]);                                 \
                if (lane == 0) atomicAdd(cnt + cur * 4 + s, cs[s]);          \
                acc[s][0] = 0.f; acc[s][1] = 0.f;                            \
                acc[s][2] = 0.f; acc[s][3] = 0.f;                            \
                cs[s] = 0.f;                                                 \
            }                                                                \
        }                                                                    \
    } while (0)

    float4 w0 = xp4[0 * 64], w1 = xp4[1 * 64], w2 = xp4[2 * 64], w3 = xp4[3 * 64];

#pragma unroll
    for (int ib = 0; ib < 32; ib += 4) {
        float4 n0, n1, n2, n3;
        if (ib + 4 < 32) {
            n0 = xp4[(ib + 4) * 64]; n1 = xp4[(ib + 5) * 64];
            n2 = xp4[(ib + 6) * 64]; n3 = xp4[(ib + 7) * 64];
        }
#pragma unroll
        for (int j = 0; j < 4; ++j) {
            float4 v = (j == 0) ? w0 : (j == 1) ? w1 : (j == 2) ? w2 : w3;
            int key = lkeys[koff + ib + j];
            int g = key >> 2, sp = key & 3;
            if (g != cur) { FLUSH_RUN(); cur = g; }
#pragma unroll
            for (int s = 0; s < 4; ++s) {
                bool m = (sp == s);
                acc[s][0] += m ? v.x : 0.f;
                acc[s][1] += m ? v.y : 0.f;
                acc[s][2] += m ? v.z : 0.f;
                acc[s][3] += m ? v.w : 0.f;
                cs[s]     += m ? 1.f : 0.f;
            }
        }
        w0 = n0; w1 = n1; w2 = n2; w3 = n3;
    }
    FLUSH_RUN();
#undef FLUSH_RUN
}

// K3: out[g][n] = S[g][:] @ Wt[:][n] + sum_s cnt[g][s]*b[s][n]
// 32-row tiles, 64 blocks, 4 waves x 64 cols.
__global__ __launch_bounds__(256) void k_gemm2(
        const float* __restrict__ S, const float* __restrict__ cnt,
        const float* __restrict__ b, const unsigned short* __restrict__ Wt,
        float* __restrict__ out) {

    __shared__ __align__(16) unsigned short Al[32 * 72];   // 4608 B
    __shared__ __align__(16) float cntL[128];              // 32 rows x 4

    int t = threadIdx.x, wave = t >> 6, lane = t & 63;
    int l15 = lane & 15, l4 = lane >> 4;
    int g0 = blockIdx.x * 32;

    if (t < 128) cntL[t] = cnt[(size_t)g0 * 4 + t];

    f32x4 acc[2][4];
#pragma unroll
    for (int m = 0; m < 2; ++m)
#pragma unroll
        for (int n = 0; n < 4; ++n) acc[m][n] = (f32x4){0.f, 0.f, 0.f, 0.f};

    for (int kbg = 0; kbg < 16; ++kbg) {
        __syncthreads();   // also covers cntL staging on first iter
        {
            int row = t >> 3, f8 = t & 7;
            const float* src = S + (size_t)(g0 + row) * KFLAT + kbg * 64 + f8 * 8;
            float4 v0 = *(const float4*)src;
            float4 v1 = *(const float4*)(src + 4);
            ushort4 u0, u1;
            u0.x = f2bf(v0.x); u0.y = f2bf(v0.y); u0.z = f2bf(v0.z); u0.w = f2bf(v0.w);
            u1.x = f2bf(v1.x); u1.y = f2bf(v1.y); u1.z = f2bf(v1.z); u1.w = f2bf(v1.w);
            *(ushort4*)(Al + row * 72 + f8 * 8)     = u0;
            *(ushort4*)(Al + row * 72 + f8 * 8 + 4) = u1;
        }
        __syncthreads();

        const unsigned short* wkb = Wt + (size_t)kbg * 16384;
#pragma unroll
        for (int ks = 0; ks < 2; ++ks) {
            int ko = ks * 32 + l4 * 8;
            bf16x8 af[2], bfr[4];
#pragma unroll
            for (int n = 0; n < 4; ++n)
                bfr[n] = *(const bf16x8*)(wkb + (size_t)(wave * 64 + n * 16 + l15) * 64 + ko);
#pragma unroll
            for (int m = 0; m < 2; ++m)
                af[m] = *(const bf16x8*)(Al + (m * 16 + l15) * 72 + ko);
#pragma unroll
            for (int m = 0; m < 2; ++m)
#pragma unroll
                for (int n = 0; n < 4; ++n)
                    acc[m][n] = __builtin_amdgcn_mfma_f32_16x16x32_bf16(
                        af[m], bfr[n], acc[m][n], 0, 0, 0);
        }
    }

    // epilogue: + sum_s cnt[row][s] * b[s][col], direct store
    float bv[4][4];
#pragma unroll
    for (int n = 0; n < 4; ++n)
#pragma unroll
        for (int s = 0; s < 4; ++s)
            bv[n][s] = b[s * 256 + wave * 64 + n * 16 + l15];

#pragma unroll
    for (int m = 0; m < 2; ++m)
#pragma unroll
        for (int r = 0; r < 4; ++r) {
            int row  = m * 16 + l4 * 4 + r;
            int grow = g0 + row;
            float4 c4 = *(const float4*)(cntL + row * 4);
            if (grow < N_STRUCT) {
#pragma unroll
                for (int n = 0; n < 4; ++n) {
                    float val = acc[m][n][r]
                              + c4.x * bv[n][0] + c4.y * bv[n][1]
                              + c4.z * bv[n][2] + c4.w * bv[n][3];
                    out[(size_t)grow * 256 + wave * 64 + n * 16 + l15] = val;
                }
            }
        }
}

extern "C" void kernel_launch(void* const* d_in, const int* in_sizes, int n_in,
                              void* d_out, int out_size, void* d_ws, size_t ws_size,
                              hipStream_t stream) {
    const float* x    = (const float*)d_in[0];
    const float* W    = (const float*)d_in[1];
    const float* b    = (const float*)d_in[2];
    const int* spec   = (const int*)d_in[3];
    const int* sidx   = (const int*)d_in[4];
    float* out        = (float*)d_out;

    char* ws = (char*)d_ws;
    unsigned short* Wt = (unsigned short*)ws;               // 524288 B
    float* S   = (float*)(ws + 524288);                     // 8388608 B
    float* cnt = (float*)(ws + 8912896);                    // 32768 B

    // zero S + cnt (contiguous)
    hipMemsetAsync(ws + 524288, 0, 8388608 + 32768, stream);

    k_wt   <<<256, 256, 0, stream>>>(W, Wt);
    k_seg  <<<(N_ATOMS + 127) / 128, 256, 0, stream>>>(x, spec, sidx, S, cnt);
    k_gemm2<<<M_PAD / 32, 256, 0, stream>>>(S, cnt, b, Wt, out);
}

// Round 4
// 70.266 us; speedup vs baseline: 2.2532x; 2.2532x over previous
//
#include <hip/hip_runtime.h>
#include <hip/hip_bf16.h>

#define N_ATOMS   200000
#define D_IN      256
#define D_OUT     256
#define N_SPECIES 4
#define N_STRUCT  2000
#define M_PAD     2048      // padded struct rows for GEMM tiling
#define KFLAT     1024      // N_SPECIES * D_IN

typedef __attribute__((ext_vector_type(8))) short bf16x8;
typedef __attribute__((ext_vector_type(4))) float f32x4;

__device__ inline unsigned short f2bf(float f) {
    unsigned int u = __float_as_uint(f);
    unsigned int r = (u + 0x7fffu + ((u >> 16) & 1u)) >> 16;   // RNE
    return (unsigned short)r;
}

// ---- ws layout (bytes) ----
// 0        : Wt  bf16 [16][256][64]   = 524288   (kbg = s*4 + (k>>6), [n][k'] per block)
// 524288   : S   bf16 [2048][1024]    = 4194304  (row g, col s*256+k; rows >=2000 stay poison)
// 4718592  : cnt f32  [2048][4]       = 32768
// 4751360  : start int[2048]          = 8192
// total ~4.76 MB

// K1: convert + transpose W -> Wt[kbg][n][kp]
__global__ void k_wt(const float* __restrict__ W, unsigned short* __restrict__ Wt) {
    int k = blockIdx.x;        // 0..255
    int n = threadIdx.x;       // 0..255
    for (int s = 0; s < N_SPECIES; ++s) {
        float v = W[((size_t)s * 256 + k) * 256 + n];
        Wt[(((size_t)(s * 4 + (k >> 6)) * 256 + n) * 64) + (k & 63)] = f2bf(v);
    }
}

// K2: CSR bounds from sorted sidx (handles empty structures; start[N_STRUCT]=N_ATOMS)
__global__ void k_bounds(const int* __restrict__ sidx, int* __restrict__ start) {
    int a = blockIdx.x * 256 + threadIdx.x;
    if (a >= N_ATOMS) return;
    int g  = sidx[a];
    int gp = (a == 0) ? -1 : sidx[a - 1];
    for (int h = gp + 1; h <= g; ++h) start[h] = a;
    if (a == N_ATOMS - 1)
        for (int h = g + 1; h <= N_STRUCT; ++h) start[h] = N_ATOMS;
}

// K3: one block per structure: stream contiguous x rows, accumulate per-species
// in registers (species wave-uniform -> scalar switch), LDS cross-wave reduce,
// single non-atomic bf16 write of S[g] + cnt[g].
__global__ __launch_bounds__(256) void k_seg2(
        const float* __restrict__ x, const int* __restrict__ spec,
        const int* __restrict__ start, unsigned short* __restrict__ S,
        float* __restrict__ cnt) {

    __shared__ __align__(16) f32x4 red[16][64];   // [w*4+s][lane] = 16 KB
    __shared__ float csl[4][4];                   // [w][s]

    int g  = blockIdx.x;
    int t  = threadIdx.x;
    int w  = t >> 6;
    int lane = t & 63;

    int s0 = start[g];
    int s1 = start[g + 1];

    f32x4 a0 = (f32x4){0.f,0.f,0.f,0.f}, a1 = a0, a2 = a0, a3 = a0;
    float c0 = 0.f, c1 = 0.f, c2 = 0.f, c3 = 0.f;

    int i = s0 + w;
    f32x4 vbuf = (f32x4){0.f,0.f,0.f,0.f};
    int spb = 0;
    if (i < s1) {
        vbuf = *(const f32x4*)(x + (size_t)i * 256 + lane * 4);
        spb  = spec[i];
    }
    while (i < s1) {
        f32x4 v = vbuf;
        int sp = __builtin_amdgcn_readfirstlane(spb);
        int nx = i + 4;
        if (nx < s1) {
            vbuf = *(const f32x4*)(x + (size_t)nx * 256 + lane * 4);
            spb  = spec[nx];
        }
        switch (sp) {
            case 0: a0 += v; c0 += 1.f; break;
            case 1: a1 += v; c1 += 1.f; break;
            case 2: a2 += v; c2 += 1.f; break;
            default: if (sp == 3) { a3 += v; c3 += 1.f; } break;
        }
        i = nx;
    }

    red[w * 4 + 0][lane] = a0;
    red[w * 4 + 1][lane] = a1;
    red[w * 4 + 2][lane] = a2;
    red[w * 4 + 3][lane] = a3;
    if (lane == 0) {
        csl[w][0] = c0; csl[w][1] = c1; csl[w][2] = c2; csl[w][3] = c3;
    }
    __syncthreads();

    {
        int s = t >> 6, l = t & 63;
        f32x4 r = red[0 + s][l] + red[4 + s][l] + red[8 + s][l] + red[12 + s][l];
        ushort4 u;
        u.x = f2bf(r[0]); u.y = f2bf(r[1]); u.z = f2bf(r[2]); u.w = f2bf(r[3]);
        *(ushort4*)(S + (size_t)g * KFLAT + s * 256 + l * 4) = u;
    }
    if (t < 4)
        cnt[g * 4 + t] = csl[0][t] + csl[1][t] + csl[2][t] + csl[3][t];
}

// K4: out[g][n] = S[g][:] @ Wt + sum_s cnt[g][s]*b[s][n]; 32-row tiles, 64 blocks.
__global__ __launch_bounds__(256) void k_gemm2(
        const unsigned short* __restrict__ S, const float* __restrict__ cnt,
        const float* __restrict__ b, const unsigned short* __restrict__ Wt,
        float* __restrict__ out) {

    __shared__ __align__(16) unsigned short Al[32 * 72];   // 4608 B
    __shared__ __align__(16) float cntL[128];              // 32 rows x 4

    int t = threadIdx.x, wave = t >> 6, lane = t & 63;
    int l15 = lane & 15, l4 = lane >> 4;
    int g0 = blockIdx.x * 32;

    if (t < 128) {
        int grow = g0 + (t >> 2);
        cntL[t] = (grow < N_STRUCT) ? cnt[(size_t)g0 * 4 + t] : 0.f;
    }

    f32x4 acc[2][4];
#pragma unroll
    for (int m = 0; m < 2; ++m)
#pragma unroll
        for (int n = 0; n < 4; ++n) acc[m][n] = (f32x4){0.f, 0.f, 0.f, 0.f};

    for (int kbg = 0; kbg < 16; ++kbg) {
        __syncthreads();   // also covers cntL staging on first iter
        {
            int row = t >> 3, f8 = t & 7;    // 8 threads x 16B = 128B per row
            int grow = g0 + row;
            ushort4 u0, u1;
            if (grow < N_STRUCT) {
                const unsigned short* src = S + (size_t)grow * KFLAT + kbg * 64 + f8 * 8;
                u0 = *(const ushort4*)src;
                u1 = *(const ushort4*)(src + 4);
            } else {
                u0 = (ushort4){0,0,0,0}; u1 = u0;
            }
            *(ushort4*)(Al + row * 72 + f8 * 8)     = u0;
            *(ushort4*)(Al + row * 72 + f8 * 8 + 4) = u1;
        }
        __syncthreads();

        const unsigned short* wkb = Wt + (size_t)kbg * 16384;
#pragma unroll
        for (int ks = 0; ks < 2; ++ks) {
            int ko = ks * 32 + l4 * 8;
            bf16x8 af[2], bfr[4];
#pragma unroll
            for (int n = 0; n < 4; ++n)
                bfr[n] = *(const bf16x8*)(wkb + (size_t)(wave * 64 + n * 16 + l15) * 64 + ko);
#pragma unroll
            for (int m = 0; m < 2; ++m)
                af[m] = *(const bf16x8*)(Al + (m * 16 + l15) * 72 + ko);
#pragma unroll
            for (int m = 0; m < 2; ++m)
#pragma unroll
                for (int n = 0; n < 4; ++n)
                    acc[m][n] = __builtin_amdgcn_mfma_f32_16x16x32_bf16(
                        af[m], bfr[n], acc[m][n], 0, 0, 0);
        }
    }

    // epilogue: + sum_s cnt[row][s] * b[s][col], direct store (no memset needed)
    float bv[4][4];
#pragma unroll
    for (int n = 0; n < 4; ++n)
#pragma unroll
        for (int s = 0; s < 4; ++s)
            bv[n][s] = b[s * 256 + wave * 64 + n * 16 + l15];

#pragma unroll
    for (int m = 0; m < 2; ++m)
#pragma unroll
        for (int r = 0; r < 4; ++r) {
            int row  = m * 16 + l4 * 4 + r;
            int grow = g0 + row;
            if (grow < N_STRUCT) {
                float4 c4 = *(const float4*)(cntL + row * 4);
#pragma unroll
                for (int n = 0; n < 4; ++n) {
                    float val = acc[m][n][r]
                              + c4.x * bv[n][0] + c4.y * bv[n][1]
                              + c4.z * bv[n][2] + c4.w * bv[n][3];
                    out[(size_t)grow * 256 + wave * 64 + n * 16 + l15] = val;
                }
            }
        }
}

extern "C" void kernel_launch(void* const* d_in, const int* in_sizes, int n_in,
                              void* d_out, int out_size, void* d_ws, size_t ws_size,
                              hipStream_t stream) {
    const float* x    = (const float*)d_in[0];
    const float* W    = (const float*)d_in[1];
    const float* b    = (const float*)d_in[2];
    const int* spec   = (const int*)d_in[3];
    const int* sidx   = (const int*)d_in[4];
    float* out        = (float*)d_out;

    char* ws = (char*)d_ws;
    unsigned short* Wt = (unsigned short*)ws;               // 524288 B
    unsigned short* S  = (unsigned short*)(ws + 524288);    // 4194304 B
    float* cnt  = (float*)(ws + 4718592);                   // 32768 B
    int* start  = (int*)(ws + 4751360);                     // 8192 B

    k_wt    <<<256, 256, 0, stream>>>(W, Wt);
    k_bounds<<<(N_ATOMS + 255) / 256, 256, 0, stream>>>(sidx, start);
    k_seg2  <<<N_STRUCT, 256, 0, stream>>>(x, spec, start, S, cnt);
    k_gemm2 <<<M_PAD / 32, 256, 0, stream>>>(S, cnt, b, Wt, out);
}

// Round 5
// 66.545 us; speedup vs baseline: 2.3792x; 1.0559x over previous
//
#include <hip/hip_runtime.h>
#include <hip/hip_bf16.h>

#define N_ATOMS   200000
#define D_IN      256
#define D_OUT     256
#define N_SPECIES 4
#define N_STRUCT  2000
#define M_PAD     2048      // padded struct rows for GEMM tiling
#define KFLAT     1024      // N_SPECIES * D_IN

typedef __attribute__((ext_vector_type(8))) short bf16x8;
typedef __attribute__((ext_vector_type(4))) float f32x4;

__device__ inline unsigned short f2bf(float f) {
    unsigned int u = __float_as_uint(f);
    unsigned int r = (u + 0x7fffu + ((u >> 16) & 1u)) >> 16;   // RNE
    return (unsigned short)r;
}

// ---- ws layout (bytes) ----
// 0        : Wt  bf16 [16][256][64]   = 524288   (kbg = s*4 + (k>>6), [n][k'] per block)
// 524288   : S   bf16 [2048][1024]    = 4194304  (rows >= 2000 stay poison, never stored)
// 4718592  : cnt f32  [2048][4]       = 32768

// K1: convert + transpose W -> Wt[kbg][n][kp]
__global__ void k_wt(const float* __restrict__ W, unsigned short* __restrict__ Wt) {
    int k = blockIdx.x;        // 0..255
    int n = threadIdx.x;       // 0..255
    for (int s = 0; s < N_SPECIES; ++s) {
        float v = W[((size_t)s * 256 + k) * 256 + n];
        Wt[(((size_t)(s * 4 + (k >> 6)) * 256 + n) * 64) + (k & 63)] = f2bf(v);
    }
}

// K2: one block per structure. Waves 0/1 find [s0,s1) via 64-ary lower_bound on
// sorted sidx; each wave streams a CONTIGUOUS quarter of rows with depth-2
// prefetch; per-species register accumulators (species wave-uniform -> scalar
// switch); LDS cross-wave reduce; single non-atomic bf16 write of S[g] + cnt[g].
__global__ __launch_bounds__(256, 8) void k_seg2(
        const float* __restrict__ x, const int* __restrict__ spec,
        const int* __restrict__ sidx, unsigned short* __restrict__ S,
        float* __restrict__ cnt) {

    __shared__ __align__(16) f32x4 red[16][64];   // [w*4+s][lane] = 16 KB
    __shared__ float csl[4][4];                   // [w][s]
    __shared__ int bnd[2];

    int g  = blockIdx.x;
    int t  = threadIdx.x;
    int w  = t >> 6;
    int lane = t & 63;

    // 64-ary lower_bound: wave w in {0,1} finds first a with sidx[a] >= g+w
    if (w < 2) {
        int key = g + w;
        int lo = 0, hi = N_ATOMS;
        while (hi - lo > 64) {
            int step = (hi - lo + 63) >> 6;
            int pos  = lo + lane * step;
            int v    = (pos < hi) ? sidx[pos] : 0x7fffffff;
            unsigned long long m = __ballot(v < key);
            int c = __popcll(m);
            int nlo = (c == 0)  ? lo : (lo + (c - 1) * step + 1);
            int nhi = (c == 64) ? hi : min(hi, lo + c * step);
            lo = nlo; hi = nhi;
        }
        {
            int pos = lo + lane;
            int v   = (pos < hi) ? sidx[pos] : 0x7fffffff;
            unsigned long long m = __ballot(v < key);
            lo += __popcll(m);
        }
        if (lane == 0) bnd[w] = lo;
    }
    __syncthreads();
    int s0 = bnd[0], s1 = bnd[1];

    // contiguous quarter per wave
    int ng = s1 - s0;
    int q  = (ng + 3) >> 2;
    int i  = s0 + w * q;
    int iE = min(s1, i + q);

    f32x4 a0 = (f32x4){0.f,0.f,0.f,0.f}, a1 = a0, a2 = a0, a3 = a0;
    float c0 = 0.f, c1 = 0.f, c2 = 0.f, c3 = 0.f;

    f32x4 b0v = a0, b1v = a0;
    int sp0 = 0, sp1 = 0;
    if (i < iE)     { b0v = *(const f32x4*)(x + (size_t)i       * 256 + lane * 4); sp0 = spec[i]; }
    if (i + 1 < iE) { b1v = *(const f32x4*)(x + (size_t)(i + 1) * 256 + lane * 4); sp1 = spec[i + 1]; }

    while (i < iE) {
        f32x4 v = b0v;
        int sp = __builtin_amdgcn_readfirstlane(sp0);
        b0v = b1v; sp0 = sp1;
        int pf = i + 2;
        if (pf < iE) {
            b1v = *(const f32x4*)(x + (size_t)pf * 256 + lane * 4);
            sp1 = spec[pf];
        }
        switch (sp) {
            case 0: a0 += v; c0 += 1.f; break;
            case 1: a1 += v; c1 += 1.f; break;
            case 2: a2 += v; c2 += 1.f; break;
            default: a3 += v; c3 += 1.f; break;
        }
        ++i;
    }

    red[w * 4 + 0][lane] = a0;
    red[w * 4 + 1][lane] = a1;
    red[w * 4 + 2][lane] = a2;
    red[w * 4 + 3][lane] = a3;
    if (lane == 0) {
        csl[w][0] = c0; csl[w][1] = c1; csl[w][2] = c2; csl[w][3] = c3;
    }
    __syncthreads();

    {
        int s = t >> 6, l = t & 63;
        f32x4 r = red[0 + s][l] + red[4 + s][l] + red[8 + s][l] + red[12 + s][l];
        ushort4 u;
        u.x = f2bf(r[0]); u.y = f2bf(r[1]); u.z = f2bf(r[2]); u.w = f2bf(r[3]);
        *(ushort4*)(S + (size_t)g * KFLAT + s * 256 + l * 4) = u;
    }
    if (t < 4)
        cnt[g * 4 + t] = csl[0][t] + csl[1][t] + csl[2][t] + csl[3][t];
}

// K3: barrier-free GEMM. 128 blocks x 4 waves; each wave owns a 16x64 tile,
// A-frags direct from S (L2/L3), B-frags direct from Wt (L2). No LDS.
__global__ __launch_bounds__(256) void k_gemm3(
        const unsigned short* __restrict__ S, const float* __restrict__ cnt,
        const float* __restrict__ b, const unsigned short* __restrict__ Wt,
        float* __restrict__ out) {

    int t = threadIdx.x, nt = t >> 6, lane = t & 63;
    int l15 = lane & 15, l4 = lane >> 4;
    int g0 = blockIdx.x * 16;

    f32x4 acc[4];
#pragma unroll
    for (int n = 0; n < 4; ++n) acc[n] = (f32x4){0.f, 0.f, 0.f, 0.f};

    const unsigned short* arow = S + (size_t)(g0 + l15) * KFLAT + l4 * 8;

#pragma unroll 4
    for (int kbg = 0; kbg < 16; ++kbg) {
        const unsigned short* wkb = Wt + (size_t)kbg * 16384 + l4 * 8;
#pragma unroll
        for (int ks = 0; ks < 2; ++ks) {
            bf16x8 af = *(const bf16x8*)(arow + kbg * 64 + ks * 32);
#pragma unroll
            for (int n = 0; n < 4; ++n) {
                bf16x8 bfr = *(const bf16x8*)(wkb + (size_t)(nt * 64 + n * 16 + l15) * 64 + ks * 32);
                acc[n] = __builtin_amdgcn_mfma_f32_16x16x32_bf16(af, bfr, acc[n], 0, 0, 0);
            }
        }
    }

    float bv[4][4];
#pragma unroll
    for (int n = 0; n < 4; ++n) {
        int col = nt * 64 + n * 16 + l15;
#pragma unroll
        for (int s = 0; s < 4; ++s) bv[n][s] = b[s * 256 + col];
    }

#pragma unroll
    for (int r = 0; r < 4; ++r) {
        int grow = g0 + l4 * 4 + r;
        if (grow < N_STRUCT) {
            float4 c4 = *(const float4*)(cnt + (size_t)grow * 4);
#pragma unroll
            for (int n = 0; n < 4; ++n) {
                int col = nt * 64 + n * 16 + l15;
                out[(size_t)grow * 256 + col] =
                    acc[n][r] + c4.x * bv[n][0] + c4.y * bv[n][1]
                              + c4.z * bv[n][2] + c4.w * bv[n][3];
            }
        }
    }
}

extern "C" void kernel_launch(void* const* d_in, const int* in_sizes, int n_in,
                              void* d_out, int out_size, void* d_ws, size_t ws_size,
                              hipStream_t stream) {
    const float* x    = (const float*)d_in[0];
    const float* W    = (const float*)d_in[1];
    const float* b    = (const float*)d_in[2];
    const int* spec   = (const int*)d_in[3];
    const int* sidx   = (const int*)d_in[4];
    float* out        = (float*)d_out;

    char* ws = (char*)d_ws;
    unsigned short* Wt = (unsigned short*)ws;               // 524288 B
    unsigned short* S  = (unsigned short*)(ws + 524288);    // 4194304 B
    float* cnt  = (float*)(ws + 4718592);                   // 32768 B

    k_wt   <<<256, 256, 0, stream>>>(W, Wt);
    k_seg2 <<<N_STRUCT, 256, 0, stream>>>(x, spec, sidx, S, cnt);
    k_gemm3<<<M_PAD / 16, 256, 0, stream>>>(S, cnt, b, Wt, out);
}